// Round 5
// baseline (228.901 us; speedup 1.0000x reference)
//
#include <hip/hip_runtime.h>
#include <math.h>

#define INFEAT 4096
#define CAPACITY 65536
#define EPS 1e-8f
#define NWAVES 8192            // 2048 blocks x 4 waves; 8 rows/wave, stride-8192

typedef float f32x4 __attribute__((ext_vector_type(4)));

#define BODY(a, b, xa, xb)                                                     \
    dot0 = fmaf((a).x, (xa).x, dot0);                                          \
    dot0 = fmaf((a).y, (xa).y, dot0);                                          \
    dot0 = fmaf((a).z, (xa).z, dot0);                                          \
    dot0 = fmaf((a).w, (xa).w, dot0);                                          \
    ss0  = fmaf((a).x, (a).x, ss0);                                            \
    ss0  = fmaf((a).y, (a).y, ss0);                                            \
    ss0  = fmaf((a).z, (a).z, ss0);                                            \
    ss0  = fmaf((a).w, (a).w, ss0);                                            \
    dot1 = fmaf((b).x, (xb).x, dot1);                                          \
    dot1 = fmaf((b).y, (xb).y, dot1);                                          \
    dot1 = fmaf((b).z, (xb).z, dot1);                                          \
    dot1 = fmaf((b).w, (xb).w, dot1);                                          \
    ss1  = fmaf((b).x, (b).x, ss1);                                            \
    ss1  = fmaf((b).y, (b).y, ss1);                                            \
    ss1  = fmaf((b).z, (b).z, ss1);                                            \
    ss1  = fmaf((b).w, (b).w, ss1);

__global__ __launch_bounds__(256) void cosine_kernel(const float* __restrict__ x,
                                                     const float* __restrict__ memory,
                                                     float* __restrict__ out) {
    const int lane = threadIdx.x & 63;
    const int wid  = threadIdx.x >> 6;
    const int wave = blockIdx.x * 4 + wid;

    // x hoisted to registers: full x vector register-resident per wave (R1).
    const f32x4* x4 = reinterpret_cast<const f32x4*>(x);
    f32x4 xr[16];
    #pragma unroll
    for (int k = 0; k < 16; ++k) xr[k] = x4[lane + k * 64];

    // Per-wave x_norm from the hoisted registers.
    float ssx = 0.f;
    #pragma unroll
    for (int k = 0; k < 16; ++k) {
        ssx = fmaf(xr[k].x, xr[k].x, ssx);
        ssx = fmaf(xr[k].y, xr[k].y, ssx);
        ssx = fmaf(xr[k].z, xr[k].z, ssx);
        ssx = fmaf(xr[k].w, xr[k].w, ssx);
    }
    #pragma unroll
    for (int off = 1; off < 64; off <<= 1) ssx += __shfl_xor(ssx, off);
    const float xn = sqrtf(ssx);

    // Per-wave column-block phase rotation (even, so pairs don't wrap):
    // decorrelates the instantaneous address phase across waves -> all HBM
    // channels busy even when waves are k-phase-locked.
    const int phase = (wave & 7) * 2;

    for (int row = wave; row < CAPACITY; row += NWAVES) {
        const f32x4* m4 =
            reinterpret_cast<const f32x4*>(memory + (size_t)row * INFEAT);
        float dot0 = 0.f, dot1 = 0.f, ss0 = 0.f, ss1 = 0.f;
        #pragma unroll
        for (int k = 0; k < 16; k += 2) {
            const int kk = (k + phase) & 15;          // even; kk+1 <= 15
            f32x4 a = __builtin_nontemporal_load(&m4[lane + kk * 64]);
            f32x4 b = __builtin_nontemporal_load(&m4[lane + (kk + 1) * 64]);
            BODY(a, b, xr[kk], xr[kk + 1])
        }
        float dot = dot0 + dot1;
        float ss  = ss0 + ss1;
        #pragma unroll
        for (int off = 32; off > 0; off >>= 1) {
            dot += __shfl_down(dot, off);
            ss  += __shfl_down(ss, off);
        }
        if (lane == 0) {
            float denom = fmaxf(sqrtf(ss) * xn, EPS);
            __builtin_nontemporal_store(dot / denom, &out[row]);
        }
    }
}

extern "C" void kernel_launch(void* const* d_in, const int* in_sizes, int n_in,
                              void* d_out, int out_size, void* d_ws, size_t ws_size,
                              hipStream_t stream) {
    const float* x      = (const float*)d_in[0];   // [4096]
    const float* memory = (const float*)d_in[1];   // [65536, 4096]
    float* out = (float*)d_out;                    // [65536]

    cosine_kernel<<<2048, 256, 0, stream>>>(x, memory, out);
}

// Round 6
// 186.148 us; speedup vs baseline: 1.2297x; 1.2297x over previous
//
#include <hip/hip_runtime.h>
#include <math.h>

#define INFEAT 4096
#define CAPACITY 65536
#define EPS 1e-8f
#define NWAVES 8192            // 2048 blocks x 4 waves, 8 rows/wave
#define RESIDENT_ROWS 14336    // 224 MiB prefix kept LLC-resident across replays

typedef float f32x4 __attribute__((ext_vector_type(4)));

// 8 fused FMAs updating (dot0,ss0) from a and (dot1,ss1) from b
#define BODY(a, b, k)                                                          \
    dot0 = fmaf((a).x, xr[k].x, dot0);                                         \
    dot0 = fmaf((a).y, xr[k].y, dot0);                                         \
    dot0 = fmaf((a).z, xr[k].z, dot0);                                         \
    dot0 = fmaf((a).w, xr[k].w, dot0);                                         \
    ss0  = fmaf((a).x, (a).x, ss0);                                            \
    ss0  = fmaf((a).y, (a).y, ss0);                                            \
    ss0  = fmaf((a).z, (a).z, ss0);                                            \
    ss0  = fmaf((a).w, (a).w, ss0);                                            \
    dot1 = fmaf((b).x, xr[(k) + 1].x, dot1);                                   \
    dot1 = fmaf((b).y, xr[(k) + 1].y, dot1);                                   \
    dot1 = fmaf((b).z, xr[(k) + 1].z, dot1);                                   \
    dot1 = fmaf((b).w, xr[(k) + 1].w, dot1);                                   \
    ss1  = fmaf((b).x, (b).x, ss1);                                            \
    ss1  = fmaf((b).y, (b).y, ss1);                                            \
    ss1  = fmaf((b).z, (b).z, ss1);                                            \
    ss1  = fmaf((b).w, (b).w, ss1);

__global__ __launch_bounds__(256) void cosine_kernel(const float* __restrict__ x,
                                                     const float* __restrict__ memory,
                                                     float* __restrict__ out) {
    const int lane = threadIdx.x & 63;
    const int wid  = threadIdx.x >> 6;
    const int wave = blockIdx.x * 4 + wid;

    // Hoist this lane's 64 x-values (16 x float4). Across the 64 lanes the
    // FULL x vector is register-resident in every wave. NOTE: all indexing of
    // xr[] below is compile-time constant (rule #20: runtime-indexed
    // ext_vector arrays spill to scratch — this killed the R4 variant).
    const f32x4* x4 = reinterpret_cast<const f32x4*>(x);
    f32x4 xr[16];
    #pragma unroll
    for (int k = 0; k < 16; ++k) xr[k] = x4[lane + k * 64];

    // Per-wave x_norm straight from the hoisted registers (no extra kernel,
    // no serialization): 64 FMAs + 6-step xor butterfly, once per wave.
    float ssx = 0.f;
    #pragma unroll
    for (int k = 0; k < 16; ++k) {
        ssx = fmaf(xr[k].x, xr[k].x, ssx);
        ssx = fmaf(xr[k].y, xr[k].y, ssx);
        ssx = fmaf(xr[k].z, xr[k].z, ssx);
        ssx = fmaf(xr[k].w, xr[k].w, ssx);
    }
    #pragma unroll
    for (int off = 1; off < 64; off <<= 1) ssx += __shfl_xor(ssx, off);
    const float xn = sqrtf(ssx);

    for (int row = wave; row < CAPACITY; row += NWAVES) {
        const f32x4* m4 =
            reinterpret_cast<const f32x4*>(memory + (size_t)row * INFEAT);
        float dot0 = 0.f, dot1 = 0.f, ss0 = 0.f, ss1 = 0.f;

        if (row < RESIDENT_ROWS) {           // wave-uniform branch
            #pragma unroll
            for (int k = 0; k < 16; k += 2) {
                f32x4 a = m4[lane + k * 64];
                f32x4 b = m4[lane + (k + 1) * 64];
                BODY(a, b, k)
            }
        } else {
            #pragma unroll
            for (int k = 0; k < 16; k += 2) {
                f32x4 a = __builtin_nontemporal_load(&m4[lane + k * 64]);
                f32x4 b = __builtin_nontemporal_load(&m4[lane + (k + 1) * 64]);
                BODY(a, b, k)
            }
        }

        float dot = dot0 + dot1;
        float ss  = ss0 + ss1;
        #pragma unroll
        for (int off = 32; off > 0; off >>= 1) {
            dot += __shfl_down(dot, off);
            ss  += __shfl_down(ss, off);
        }
        if (lane == 0) {
            float denom = fmaxf(sqrtf(ss) * xn, EPS);
            __builtin_nontemporal_store(dot / denom, &out[row]);
        }
    }
}

extern "C" void kernel_launch(void* const* d_in, const int* in_sizes, int n_in,
                              void* d_out, int out_size, void* d_ws, size_t ws_size,
                              hipStream_t stream) {
    const float* x      = (const float*)d_in[0];   // [4096]
    const float* memory = (const float*)d_in[1];   // [65536, 4096]
    float* out = (float*)d_out;                    // [65536]

    cosine_kernel<<<2048, 256, 0, stream>>>(x, memory, out);
}

// Round 7
// 163.272 us; speedup vs baseline: 1.4020x; 1.1401x over previous
//
#include <hip/hip_runtime.h>
#include <math.h>

#define INFEAT 4096
#define CAPACITY 65536
#define EPS 1e-8f
#define NWAVES 8192            // 2048 blocks x 4 waves; 2 rows/wave/iter, 4 iters

typedef float f32x4 __attribute__((ext_vector_type(4)));

// 8 fused FMAs: (dotP,ssP) += row-vec a vs x-frag xr[k]; 2-way ILP via P in {A0,A1,B0,B1}
#define BODY(P0, P1, a, b, k)                                                  \
    dot##P0 = fmaf((a).x, xr[k].x, dot##P0);                                   \
    dot##P0 = fmaf((a).y, xr[k].y, dot##P0);                                   \
    dot##P0 = fmaf((a).z, xr[k].z, dot##P0);                                   \
    dot##P0 = fmaf((a).w, xr[k].w, dot##P0);                                   \
    ss##P0  = fmaf((a).x, (a).x, ss##P0);                                      \
    ss##P0  = fmaf((a).y, (a).y, ss##P0);                                      \
    ss##P0  = fmaf((a).z, (a).z, ss##P0);                                      \
    ss##P0  = fmaf((a).w, (a).w, ss##P0);                                      \
    dot##P1 = fmaf((b).x, xr[(k) + 1].x, dot##P1);                             \
    dot##P1 = fmaf((b).y, xr[(k) + 1].y, dot##P1);                             \
    dot##P1 = fmaf((b).z, xr[(k) + 1].z, dot##P1);                             \
    dot##P1 = fmaf((b).w, xr[(k) + 1].w, dot##P1);                             \
    ss##P1  = fmaf((b).x, (b).x, ss##P1);                                      \
    ss##P1  = fmaf((b).y, (b).y, ss##P1);                                      \
    ss##P1  = fmaf((b).z, (b).z, ss##P1);                                      \
    ss##P1  = fmaf((b).w, (b).w, ss##P1);

__global__ __launch_bounds__(256) void cosine_kernel(const float* __restrict__ x,
                                                     const float* __restrict__ memory,
                                                     float* __restrict__ out) {
    const int lane = threadIdx.x & 63;
    const int wid  = threadIdx.x >> 6;
    const int wave = blockIdx.x * 4 + wid;

    // x hoisted to registers (R1). All xr[] indexing below is compile-time
    // constant (rule #20).
    const f32x4* x4 = reinterpret_cast<const f32x4*>(x);
    f32x4 xr[16];
    #pragma unroll
    for (int k = 0; k < 16; ++k) xr[k] = x4[lane + k * 64];

    float ssx = 0.f;
    #pragma unroll
    for (int k = 0; k < 16; ++k) {
        ssx = fmaf(xr[k].x, xr[k].x, ssx);
        ssx = fmaf(xr[k].y, xr[k].y, ssx);
        ssx = fmaf(xr[k].z, xr[k].z, ssx);
        ssx = fmaf(xr[k].w, xr[k].w, ssx);
    }
    #pragma unroll
    for (int off = 1; off < 64; off <<= 1) ssx += __shfl_xor(ssx, off);
    const float xn = sqrtf(ssx);

    // Dual-row interleave: rows (2w, 2w+1), step 16384. All waves sweep a
    // moving 256 MB window together (channel balance preserved); one
    // vmcnt-drain + reduce per 32 KB instead of per 16 KB; two independent
    // load streams per wave (~2x MLP).
    for (int r0 = 2 * wave; r0 < CAPACITY; r0 += 2 * NWAVES) {
        const f32x4* mA =
            reinterpret_cast<const f32x4*>(memory + (size_t)r0 * INFEAT);
        const f32x4* mB =
            reinterpret_cast<const f32x4*>(memory + (size_t)(r0 + 1) * INFEAT);
        float dotA0 = 0.f, dotA1 = 0.f, ssA0 = 0.f, ssA1 = 0.f;
        float dotB0 = 0.f, dotB1 = 0.f, ssB0 = 0.f, ssB1 = 0.f;
        #pragma unroll
        for (int k = 0; k < 16; k += 2) {
            f32x4 a = __builtin_nontemporal_load(&mA[lane + k * 64]);
            f32x4 b = __builtin_nontemporal_load(&mA[lane + (k + 1) * 64]);
            f32x4 c = __builtin_nontemporal_load(&mB[lane + k * 64]);
            f32x4 d = __builtin_nontemporal_load(&mB[lane + (k + 1) * 64]);
            BODY(A0, A1, a, b, k)
            BODY(B0, B1, c, d, k)
        }
        float dotA = dotA0 + dotA1, ssA = ssA0 + ssA1;
        float dotB = dotB0 + dotB1, ssB = ssB0 + ssB1;
        #pragma unroll
        for (int off = 32; off > 0; off >>= 1) {
            dotA += __shfl_down(dotA, off);
            ssA  += __shfl_down(ssA, off);
            dotB += __shfl_down(dotB, off);
            ssB  += __shfl_down(ssB, off);
        }
        if (lane == 0) {
            __builtin_nontemporal_store(
                dotA / fmaxf(sqrtf(ssA) * xn, EPS), &out[r0]);
            __builtin_nontemporal_store(
                dotB / fmaxf(sqrtf(ssB) * xn, EPS), &out[r0 + 1]);
        }
    }
}

extern "C" void kernel_launch(void* const* d_in, const int* in_sizes, int n_in,
                              void* d_out, int out_size, void* d_ws, size_t ws_size,
                              hipStream_t stream) {
    const float* x      = (const float*)d_in[0];   // [4096]
    const float* memory = (const float*)d_in[1];   // [65536, 4096]
    float* out = (float*)d_out;                    // [65536]

    cosine_kernel<<<2048, 256, 0, stream>>>(x, memory, out);
}